// Round 1
// baseline (177.191 us; speedup 1.0000x reference)
//
#include <hip/hip_runtime.h>
#include <stdint.h>

// Problem constants
#define BATCH 4096
#define DDIM  768
#define EDIM  512
#define NSPLIT 8            // column splits in flash pass
#define LOG2E 1.44269504088896340736f
#define NEGBIG (-3.402823466e38f)

using short8  = __attribute__((ext_vector_type(8))) short;
using float4v = __attribute__((ext_vector_type(4))) float;

__device__ __forceinline__ unsigned short f2bf(float x) {
    union { float f; uint32_t u; } v; v.f = x;
    uint32_t u = v.u;
    u += 0x7FFFu + ((u >> 16) & 1u);   // round-to-nearest-even
    return (unsigned short)(u >> 16);
}
__device__ __forceinline__ float bf2f(unsigned short h) {
    union { uint32_t u; float f; } v; v.u = ((uint32_t)h) << 16;
    return v.f;
}

// ---------------- fp32 -> bf16 elementwise ----------------
__global__ void cvt_bf16(const float* __restrict__ in, unsigned short* __restrict__ out, int n4) {
    int i = blockIdx.x * blockDim.x + threadIdx.x;
    if (i >= n4) return;
    float4 v = ((const float4*)in)[i];
    ushort4 o;
    o.x = f2bf(v.x); o.y = f2bf(v.y); o.z = f2bf(v.z); o.w = f2bf(v.w);
    ((ushort4*)out)[i] = o;
}

// ---------------- W (K x N fp32) -> Wt (N x K bf16) ----------------
__global__ void transpose_cvt(const float* __restrict__ W, unsigned short* __restrict__ Wt,
                              int K, int N) {
    __shared__ float tile[32][33];
    int n0 = blockIdx.x * 32, k0 = blockIdx.y * 32;
    int tid = threadIdx.x;
    for (int p = 0; p < 4; ++p) {
        int e = tid + p * 256; int lr = e >> 5, lc = e & 31;
        tile[lc][lr] = W[(k0 + lr) * N + n0 + lc];
    }
    __syncthreads();
    for (int p = 0; p < 4; ++p) {
        int e = tid + p * 256; int lr = e >> 5, lc = e & 31;
        Wt[(n0 + lr) * K + (k0 + lc)] = f2bf(tile[lr][lc]);
    }
}

// ---------------- NT GEMM: C[MxN] f32 = A[MxK] bf16 @ B[NxK]^T bf16 ----------------
// block 256 (4 waves), tile BM=128 x BN=64, BK=32; wave w computes rows [32w,32w+32)
__global__ __launch_bounds__(256) void gemm_nt(const unsigned short* __restrict__ A,
                                               const unsigned short* __restrict__ Bm,
                                               float* __restrict__ C, int M, int N, int K) {
    __shared__ __align__(16) unsigned short As[128 * 32];
    __shared__ __align__(16) unsigned short Bs[64 * 32];
    int tid = threadIdx.x;
    int wave = tid >> 6, lane = tid & 63;
    int q = lane >> 4, r = lane & 15;
    int m0 = blockIdx.x * 128, n0 = blockIdx.y * 64;
    float4v acc[2][4];
    for (int a = 0; a < 2; ++a) for (int t = 0; t < 4; ++t) acc[a][t] = (float4v){0.f,0.f,0.f,0.f};
    int nch = K >> 5;
    for (int kc = 0; kc < nch; ++kc) {
        int k0 = kc << 5;
        __syncthreads();
        for (int i = 0; i < 2; ++i) {
            int u = tid + i * 256;
            int row = u >> 2, kp = u & 3;
            *(short8*)&As[u * 8] = *(const short8*)&A[(size_t)(m0 + row) * K + k0 + kp * 8];
        }
        {
            int row = tid >> 2, kp = tid & 3;
            *(short8*)&Bs[tid * 8] = *(const short8*)&Bm[(size_t)(n0 + row) * K + k0 + kp * 8];
        }
        __syncthreads();
        short8 af0 = *(const short8*)&As[(wave * 32 + r) * 32 + q * 8];
        short8 af1 = *(const short8*)&As[(wave * 32 + 16 + r) * 32 + q * 8];
        for (int t = 0; t < 4; ++t) {
            short8 bf = *(const short8*)&Bs[(t * 16 + r) * 32 + q * 8];
            acc[0][t] = __builtin_amdgcn_mfma_f32_16x16x32_bf16(af0, bf, acc[0][t], 0, 0, 0);
            acc[1][t] = __builtin_amdgcn_mfma_f32_16x16x32_bf16(af1, bf, acc[1][t], 0, 0, 0);
        }
    }
    for (int rt = 0; rt < 2; ++rt)
        for (int t = 0; t < 4; ++t)
            for (int g = 0; g < 4; ++g) {
                int row = m0 + wave * 32 + rt * 16 + q * 4 + g;
                int col = n0 + t * 16 + r;
                C[(size_t)row * N + col] = acc[rt][t][g];
            }
}

// ---------------- row L2-normalize: f32[4096x512] -> bf16[4096x512] ----------------
__global__ void norm_rows(const float* __restrict__ Cin, unsigned short* __restrict__ outn) {
    int wave = threadIdx.x >> 6, lane = threadIdx.x & 63;
    int row = blockIdx.x * 4 + wave;
    const float4* rp = (const float4*)&Cin[(size_t)row * 512];
    float4 v0 = rp[lane * 2], v1 = rp[lane * 2 + 1];
    float s = v0.x*v0.x + v0.y*v0.y + v0.z*v0.z + v0.w*v0.w
            + v1.x*v1.x + v1.y*v1.y + v1.z*v1.z + v1.w*v1.w;
    for (int off = 1; off < 64; off <<= 1) s += __shfl_xor(s, off);
    float rn = rsqrtf(s);
    union { unsigned short us[8]; uint4 u4; } o;
    o.us[0] = f2bf(v0.x * rn); o.us[1] = f2bf(v0.y * rn);
    o.us[2] = f2bf(v0.z * rn); o.us[3] = f2bf(v0.w * rn);
    o.us[4] = f2bf(v1.x * rn); o.us[5] = f2bf(v1.y * rn);
    o.us[6] = f2bf(v1.z * rn); o.us[7] = f2bf(v1.w * rn);
    *(uint4*)&outn[(size_t)row * 512 + lane * 8] = o.u4;
}

// ---------------- t_i = scale * dot(img_n[i], txt_n[labels[i]]) ----------------
__global__ void tdot(const unsigned short* __restrict__ img, const unsigned short* __restrict__ txt,
                     const int* __restrict__ labels, const float* __restrict__ ls,
                     float* __restrict__ tout) {
    int wave = threadIdx.x >> 6, lane = threadIdx.x & 63;
    int row = blockIdx.x * 4 + wave;
    int lab = labels[row];
    union { unsigned short us[8]; uint4 u4; } a, b;
    a.u4 = *(const uint4*)&img[(size_t)row * 512 + lane * 8];
    b.u4 = *(const uint4*)&txt[(size_t)lab * 512 + lane * 8];
    float s = 0.f;
    for (int j = 0; j < 8; ++j) s += bf2f(a.us[j]) * bf2f(b.us[j]);
    for (int off = 1; off < 64; off <<= 1) s += __shfl_xor(s, off);
    if (lane == 0) tout[row] = expf(ls[0]) * s;
}

// ---------------- fused logits + online softmax + masked denom ----------------
// grid (64 rowblocks, 8 col-splits); block 256 = 4 waves; wave handles 16 rows x 512 cols
__global__ __launch_bounds__(256) void flash_pass(
    const unsigned short* __restrict__ img, const unsigned short* __restrict__ txt,
    const int* __restrict__ labels, const float* __restrict__ tvals,
    const float* __restrict__ ls,
    float* __restrict__ mP, float* __restrict__ lP, float* __restrict__ dP) {
    __shared__ __align__(16) unsigned short Bs[8 * 64 * 32];  // 32 KB: [kc][n][kk]
    int tid = threadIdx.x;
    int wave = tid >> 6, lane = tid & 63;
    int q = lane >> 4, r = lane & 15;
    int row0 = blockIdx.x * 64 + wave * 16;
    int split = blockIdx.y;
    float alpha = expf(ls[0]);

    // A fragments (16 rows x 512 K) register-resident: 16 chunks of K=32
    short8 af[16];
    for (int kc = 0; kc < 16; ++kc)
        af[kc] = *(const short8*)&img[(size_t)(row0 + r) * 512 + kc * 32 + q * 8];

    int labr[4]; float tr[4];
    for (int g = 0; g < 4; ++g) {
        int rw = row0 + q * 4 + g;
        labr[g] = labels[rw];
        tr[g] = tvals[rw];
    }
    float m[4], l[4], d[4];
    for (int g = 0; g < 4; ++g) { m[g] = NEGBIG; l[g] = 0.f; d[g] = 0.f; }

    for (int ct = 0; ct < 8; ++ct) {
        int colbase = split * 512 + ct * 64;
        float4v acc[4];
        for (int t = 0; t < 4; ++t) acc[t] = (float4v){0.f,0.f,0.f,0.f};
        for (int h = 0; h < 2; ++h) {
            __syncthreads();
            int brow = tid >> 2, kp = tid & 3;
            for (int i = 0; i < 8; ++i) {
                *(short8*)&Bs[((i * 64 + brow) * 32) + kp * 8] =
                    *(const short8*)&txt[(size_t)(colbase + brow) * 512 + h * 256 + i * 32 + kp * 8];
            }
            __syncthreads();
            for (int kc = 0; kc < 8; ++kc) {
                short8 a = af[h * 8 + kc];
                for (int t = 0; t < 4; ++t) {
                    short8 bf = *(const short8*)&Bs[(kc * 64 + t * 16 + r) * 32 + q * 8];
                    acc[t] = __builtin_amdgcn_mfma_f32_16x16x32_bf16(a, bf, acc[t], 0, 0, 0);
                }
            }
        }
        // online softmax update for this 16x64 slice
        int labc[4];
        for (int t = 0; t < 4; ++t) labc[t] = labels[colbase + t * 16 + r];
        float s[4][4];
        for (int t = 0; t < 4; ++t)
            for (int g = 0; g < 4; ++g) s[t][g] = acc[t][g] * alpha;
        for (int g = 0; g < 4; ++g) {
            float mx = fmaxf(fmaxf(s[0][g], s[1][g]), fmaxf(s[2][g], s[3][g]));
            for (int off = 1; off < 16; off <<= 1) mx = fmaxf(mx, __shfl_xor(mx, off));
            float mn = fmaxf(m[g], mx);
            float c = exp2f((m[g] - mn) * LOG2E);
            float ps = 0.f, qs = 0.f;
            for (int t = 0; t < 4; ++t) {
                float p = exp2f((s[t][g] - mn) * LOG2E);
                ps += p;
                bool msk = (s[t][g] > tr[g]) && (labc[t] != labr[g]);
                qs += msk ? p : 0.f;
            }
            for (int off = 1; off < 16; off <<= 1) {
                ps += __shfl_xor(ps, off);
                qs += __shfl_xor(qs, off);
            }
            m[g] = mn;
            l[g] = l[g] * c + ps;
            d[g] = d[g] * c + qs;
        }
    }
    if (r == 0) {
        for (int g = 0; g < 4; ++g) {
            int rw = row0 + q * 4 + g;
            int idx = split * BATCH + rw;
            mP[idx] = m[g]; lP[idx] = l[g]; dP[idx] = d[g];
        }
    }
}

// ---------------- merge splits, per-row losses, block partial sums ----------------
__global__ void combine(const float* __restrict__ mP, const float* __restrict__ lP,
                        const float* __restrict__ dP, const float* __restrict__ tvals,
                        float* __restrict__ partials) {
    int tid = threadIdx.x;
    int row = blockIdx.x * 256 + tid;
    float mv[NSPLIT];
    float M = NEGBIG;
    for (int s = 0; s < NSPLIT; ++s) { mv[s] = mP[s * BATCH + row]; M = fmaxf(M, mv[s]); }
    float L = 0.f, D = 0.f;
    for (int s = 0; s < NSPLIT; ++s) {
        float c = exp2f((mv[s] - M) * LOG2E);
        L += lP[s * BATCH + row] * c;
        D += dP[s * BATCH + row] * c;
    }
    float tv = tvals[row];
    float logL = logf(L);
    float clip = -(tv - M - logL);
    float py = exp2f((tv - M) * LOG2E) / L;
    float cmp = (D > 0.f) ? (py / (D / L + 1e-10f)) : 0.f;
    float v = clip + cmp;
    for (int off = 1; off < 64; off <<= 1) v += __shfl_xor(v, off);
    __shared__ float ws4[4];
    int wave = tid >> 6, lane = tid & 63;
    if (lane == 0) ws4[wave] = v;
    __syncthreads();
    if (tid == 0) partials[blockIdx.x] = ws4[0] + ws4[1] + ws4[2] + ws4[3];
}

__global__ void final_sum(const float* __restrict__ partials, float* __restrict__ out) {
    int tid = threadIdx.x;
    float v = (tid < 16) ? partials[tid] : 0.f;
    for (int off = 1; off < 64; off <<= 1) v += __shfl_xor(v, off);
    if (tid == 0) out[0] = v * (1.0f / 4096.0f);
}

extern "C" void kernel_launch(void* const* d_in, const int* in_sizes, int n_in,
                              void* d_out, int out_size, void* d_ws, size_t ws_size,
                              hipStream_t stream) {
    const float* images = (const float*)d_in[0];
    const float* texts  = (const float*)d_in[1];
    const int*   labels = (const int*)d_in[2];
    const float* W_img  = (const float*)d_in[3];
    const float* W_txt  = (const float*)d_in[4];
    const float* lscale = (const float*)d_in[5];
    float* out = (float*)d_out;

    char* ws = (char*)d_ws;
    unsigned short* img_bf = (unsigned short*)(ws + 0);           // 6,291,456 B
    unsigned short* txt_bf = (unsigned short*)(ws + 6291456);     // 6,291,456 B
    unsigned short* wt_img = (unsigned short*)(ws + 12582912);    //   786,432 B
    unsigned short* wt_txt = (unsigned short*)(ws + 13369344);    //   786,432 B
    float*          proj   = (float*)(ws + 14155776);             // 8,388,608 B (reused)
    unsigned short* img_n  = (unsigned short*)(ws + 22544384);    // 4,194,304 B
    unsigned short* txt_n  = (unsigned short*)(ws + 26738688);    // 4,194,304 B
    float*          tvals  = (float*)(ws + 30932992);             //    16,384 B
    float*          mP     = (float*)(ws + 30949376);             //   131,072 B
    float*          lP     = (float*)(ws + 31080448);             //   131,072 B
    float*          dP     = (float*)(ws + 31211520);             //   131,072 B
    float*          parts  = (float*)(ws + 31342592);             //        64 B

    cvt_bf16<<<3072, 256, 0, stream>>>(images, img_bf, (BATCH * DDIM) / 4);
    cvt_bf16<<<3072, 256, 0, stream>>>(texts,  txt_bf, (BATCH * DDIM) / 4);
    transpose_cvt<<<dim3(EDIM / 32, DDIM / 32), 256, 0, stream>>>(W_img, wt_img, DDIM, EDIM);
    transpose_cvt<<<dim3(EDIM / 32, DDIM / 32), 256, 0, stream>>>(W_txt, wt_txt, DDIM, EDIM);
    gemm_nt<<<dim3(BATCH / 128, EDIM / 64), 256, 0, stream>>>(img_bf, wt_img, proj, BATCH, EDIM, DDIM);
    norm_rows<<<BATCH / 4, 256, 0, stream>>>(proj, img_n);
    gemm_nt<<<dim3(BATCH / 128, EDIM / 64), 256, 0, stream>>>(txt_bf, wt_txt, proj, BATCH, EDIM, DDIM);
    norm_rows<<<BATCH / 4, 256, 0, stream>>>(proj, txt_n);
    tdot<<<BATCH / 4, 256, 0, stream>>>(img_n, txt_n, labels, lscale, tvals);
    flash_pass<<<dim3(BATCH / 64, NSPLIT), 256, 0, stream>>>(img_n, txt_n, labels, tvals, lscale,
                                                             mP, lP, dP);
    combine<<<16, 256, 0, stream>>>(mP, lP, dP, tvals, parts);
    final_sum<<<1, 64, 0, stream>>>(parts, out);
}